// Round 13
// baseline (568.703 us; speedup 1.0000x reference)
//
#include <hip/hip_runtime.h>
#include <math.h>

// Problem constants
#define B_    64
#define S_    4096
#define HID   64
#define LIFT  256
#define MODES 16
#define NL    4

// Workspace layout (float-sized slots). Total 17,101,824 <= proven 17,108,992.
#define OFF_H     0                       // packed h (uint): B*HID*S = 16,777,216
#define OFF_ETB   16777216                // packed twiddles Etab[s][32]: 131,072
#define OFF_XFY   (OFF_ETB + 131072)      // xf fp32 [b][i][32] OR packed yk [b][o][32]
#define OFF_SKH   (OFF_XFY + 131072)      // ushort skip hi [l][o][c]: 8192 floats
#define OFF_SKL   (OFF_SKH + 8192)
#define OFF_W2HI  (OFF_SKL + 8192)        // ushort lift w2 hi [o][c2]
#define OFF_W2LO  (OFF_W2HI + 8192)
#define OFF_P1HI  (OFF_W2LO + 8192)       // ushort proj w1 hi [c2][c]
#define OFF_P1LO  (OFF_P1HI + 8192)
#define OFF_PART  (OFF_P1LO + 8192)       // 12,288 (atomic-accumulated)
#define OFF_W1B   (OFF_PART + 12288)      // float4[256]: (w1x, w1y, b1, 0)

typedef short short8 __attribute__((ext_vector_type(8)));
typedef float f32x4  __attribute__((ext_vector_type(4)));
typedef unsigned uint8v __attribute__((ext_vector_type(8)));
#define MFMA16 __builtin_amdgcn_mfma_f32_16x16x32_bf16

// Branch-free gelu via A&S 7.1.26 erf (max abs err 1.5e-7 — same order as
// the bf16-split noise already in the pipeline). ~14 VALU ops vs ~35 for
// libm erff's dual-path masked execution.
__device__ __forceinline__ float gelu_f(float x) {
  float t  = 0.70710678118654752440f * x;
  float at = fabsf(t);
  float k  = __frcp_rn(1.0f + 0.3275911f * at);
  float p  = ((((1.061405429f * k - 1.453152027f) * k + 1.421413741f) * k
               - 0.284496736f) * k + 0.254829592f) * k;
  float e  = __expf(-at * at);
  float erf_abs = 1.0f - p * e;
  float erf_v = copysignf(erf_abs, t);
  return 0.5f * x * (1.0f + erf_v);
}
__device__ __forceinline__ unsigned short f2bf(float x) {   // RNE
  unsigned u = __float_as_uint(x);
  u += 0x7fffu + ((u >> 16) & 1u);
  return (unsigned short)(u >> 16);
}
__device__ __forceinline__ float bf2f(unsigned short b) {
  return __uint_as_float(((unsigned)b) << 16);
}
__device__ __forceinline__ unsigned packsplit(float x) {    // hi | lo<<16
  unsigned short hi = f2bf(x);
  unsigned short lo = f2bf(x - bf2f(hi));
  return (unsigned)hi | ((unsigned)lo << 16);
}
__device__ __forceinline__ void unpk8(const unsigned* pk, short8& h8, short8& l8) {
  #pragma unroll
  for (int j = 0; j < 8; ++j) {
    unsigned u = pk[j];
    h8[j] = (short)(u & 0xffffu);
    l8[j] = (short)(u >> 16);
  }
}

// ---------------------------------------------------------------- init ----
// grid 256. Twiddles via sincosf (bf16-split pack error dominates).
__global__ void k_init(const float* __restrict__ lift_w2,
                       const float* __restrict__ skip_w,
                       const float* __restrict__ proj_w1,
                       const float* __restrict__ lift_w1,
                       const float* __restrict__ lift_b1,
                       float* __restrict__ ws) {
  unsigned* etab = (unsigned*)(ws + OFF_ETB);
  unsigned short* skh = (unsigned short*)(ws + OFF_SKH);
  unsigned short* skl = (unsigned short*)(ws + OFF_SKL);
  unsigned short* w2hi = (unsigned short*)(ws + OFF_W2HI);
  unsigned short* w2lo = (unsigned short*)(ws + OFF_W2LO);
  unsigned short* p1hi = (unsigned short*)(ws + OFF_P1HI);
  unsigned short* p1lo = (unsigned short*)(ws + OFF_P1LO);
  float4* w1b = (float4*)(ws + OFF_W1B);
  int idx = blockIdx.x * 256 + threadIdx.x;
  int stride = gridDim.x * 256;
  // Etab[s][c]: c<16 -> cos(th*m*s), c>=16 -> -sin(th*m*s), m = c&15 (s-major)
  for (int k = idx; k < 4096 * 32; k += stride) {
    int s = k >> 5, c = k & 31;
    int m = c & 15;
    int r = (m * s) & 4095;
    float th = (float)(2.0 * 3.14159265358979323846 / 4096.0) * (float)r;
    float sn, cn; sincosf(th, &sn, &cn);
    float v = (c < 16) ? cn : -sn;
    etab[k] = packsplit(v);
  }
  for (int k = idx; k < NL * HID * HID; k += stride) {  // natural [l][o][c]
    float w = skip_w[k];
    unsigned short hi = f2bf(w);
    skh[k] = hi; skl[k] = f2bf(w - bf2f(hi));
  }
  for (int k = idx; k < HID * LIFT; k += stride) {      // natural [o][c2]
    float w = lift_w2[k];
    unsigned short hi = f2bf(w);
    w2hi[k] = hi; w2lo[k] = f2bf(w - bf2f(hi));
  }
  for (int k = idx; k < LIFT * HID; k += stride) {      // natural [c2][c]
    float w = proj_w1[k];
    unsigned short hi = f2bf(w);
    p1hi[k] = hi; p1lo[k] = f2bf(w - bf2f(hi));
  }
  for (int k = idx; k < LIFT; k += stride) {            // packed lift stage-1
    w1b[k] = make_float4(lift_w1[2 * k], lift_w1[2 * k + 1], lift_b1[k], 0.f);
  }
  for (int k = idx; k < 12288; k += stride)             // zero part (atomics)
    ws[OFF_PART + k] = 0.f;
}

// ---------------------------------------------------------------- lift ----
// grid (S/256, B), block 256 (4 waves). Wave owns 64 s-cols (nt=0..3);
// per kstep the 8 A-frags + 8 W1B rows are loaded ONCE and amortized over
// 4 gelu-bursts + 48 MFMAs.  (r8-proven)
__global__ __launch_bounds__(256, 2) void k_lift(
    const float* __restrict__ x, const float4* __restrict__ W1B,
    const float* __restrict__ b2,
    const unsigned short* __restrict__ Whi,
    const unsigned short* __restrict__ Wlo,
    unsigned* __restrict__ Hp) {
  int tid = threadIdx.x;
  int b = blockIdx.y, s0 = blockIdx.x * 256;
  int lane = tid & 63, wv = tid >> 6, quad = lane >> 4, n16 = lane & 15;
  int sw = s0 + wv * 64;
  int cq = quad * 8;    // lane's j-base inside each 32-row K-chunk
  float2 xv[4];
  #pragma unroll
  for (int nt = 0; nt < 4; ++nt)
    xv[nt] = ((const float2*)x)[b * S_ + sw + nt * 16 + n16];
  f32x4 acc[4][4];
  #pragma unroll
  for (int mt = 0; mt < 4; ++mt)
    #pragma unroll
    for (int nt = 0; nt < 4; ++nt) acc[mt][nt] = (f32x4){0.f, 0.f, 0.f, 0.f};

  #pragma unroll 1
  for (int k = 0; k < 8; ++k) {
    short8 ah[4], al[4];
    #pragma unroll
    for (int mt = 0; mt < 4; ++mt) {
      int aoff = (mt * 16 + n16) * 256 + k * 32 + cq;
      ah[mt] = *(const short8*)(Whi + aoff);
      al[mt] = *(const short8*)(Wlo + aoff);
    }
    float4 w[8];
    #pragma unroll
    for (int j = 0; j < 8; ++j) w[j] = W1B[k * 32 + cq + j];
    #pragma unroll
    for (int nt = 0; nt < 4; ++nt) {
      short8 bh, bl;
      #pragma unroll
      for (int j = 0; j < 8; ++j) {
        float t = gelu_f(w[j].x * xv[nt].x + w[j].y * xv[nt].y + w[j].z);
        unsigned pk = packsplit(t);
        bh[j] = (short)(pk & 0xffffu);
        bl[j] = (short)(pk >> 16);
      }
      #pragma unroll
      for (int mt = 0; mt < 4; ++mt) {
        acc[mt][nt] = MFMA16(ah[mt], bh, acc[mt][nt], 0, 0, 0);
        acc[mt][nt] = MFMA16(ah[mt], bl, acc[mt][nt], 0, 0, 0);
        acc[mt][nt] = MFMA16(al[mt], bh, acc[mt][nt], 0, 0, 0);
      }
    }
  }
  #pragma unroll
  for (int mt = 0; mt < 4; ++mt) {
    int o0 = mt * 16 + quad * 4;
    float4 bb = *(const float4*)&b2[o0];
    #pragma unroll
    for (int nt = 0; nt < 4; ++nt) {
      int sc = sw + nt * 16 + n16;
      unsigned* hp = Hp + ((size_t)b * HID + o0) * S_ + sc;
      hp[0]            = packsplit(acc[mt][nt][0] + bb.x);
      hp[(size_t)S_]   = packsplit(acc[mt][nt][1] + bb.y);
      hp[(size_t)2*S_] = packsplit(acc[mt][nt][2] + bb.z);
      hp[(size_t)3*S_] = packsplit(acc[mt][nt][3] + bb.w);
    }
  }
}

// --------------------------------------------------------- forward DFT ----
// grid (4 msplit, B, 4 ksplit), block 256 (4 waves) -> 1024 blocks, 4/CU.
// Wave g = ks*4+wv covers K-range [g*256, +256). Block partial is LDS-
// reduced then atomicAdd'ed into xf (16 commutative fp32 contributors).
// xf zeroed per layer by hipMemsetAsync before this kernel.
__global__ __launch_bounds__(256, 4) void k_fft_fwd(
    const unsigned* __restrict__ Hp, const unsigned* __restrict__ Etab,
    float* __restrict__ xf) {
  __shared__ float red[4 * 512];
  int tid = threadIdx.x;
  int i0 = blockIdx.x * 16, b = blockIdx.y, ks = blockIdx.z;
  int lane = tid & 63, wv = tid >> 6, quad = lane >> 4, n16 = lane & 15;
  const unsigned* hb = Hp + ((size_t)b * HID + i0 + n16) * S_;
  int g = ks * 4 + wv;               // K-chunk 0..15
  f32x4 acc0 = (f32x4){0.f,0.f,0.f,0.f}, acc1 = (f32x4){0.f,0.f,0.f,0.f};
  #pragma unroll 1
  for (int kt = 0; kt < 8; ++kt) {
    int sb = g * 256 + kt * 32 + quad * 8;
    uint8v av = *(const uint8v*)(hb + sb);
    short8 ah, al;
    #pragma unroll
    for (int j = 0; j < 8; ++j) {
      unsigned u = av[j];
      ah[j] = (short)(u & 0xffffu); al[j] = (short)(u >> 16);
    }
    unsigned q0[8], q1[8];
    #pragma unroll
    for (int j = 0; j < 8; ++j) {
      q0[j] = Etab[(sb + j) * 32 + n16];
      q1[j] = Etab[(sb + j) * 32 + 16 + n16];
    }
    short8 bh0, bl0, bh1, bl1;
    unpk8(q0, bh0, bl0);
    unpk8(q1, bh1, bl1);
    acc0 = MFMA16(ah, bh0, acc0, 0, 0, 0);
    acc0 = MFMA16(ah, bl0, acc0, 0, 0, 0);
    acc0 = MFMA16(al, bh0, acc0, 0, 0, 0);
    acc1 = MFMA16(ah, bh1, acc1, 0, 0, 0);
    acc1 = MFMA16(ah, bl1, acc1, 0, 0, 0);
    acc1 = MFMA16(al, bh1, acc1, 0, 0, 0);
  }
  // D: row = quad*4+r (i_local), col = n16 (+16 for acc1)
  #pragma unroll
  for (int r = 0; r < 4; ++r) {
    red[wv * 512 + (quad * 4 + r) * 32 + n16]      = acc0[r];
    red[wv * 512 + (quad * 4 + r) * 32 + 16 + n16] = acc1[r];
  }
  __syncthreads();
  #pragma unroll
  for (int u = 0; u < 2; ++u) {
    int t = u * 256 + tid;
    int il = t >> 5, c = t & 31;
    float v = red[t] + red[512 + t] + red[1024 + t] + red[1536 + t];
    atomicAdd(&xf[(size_t)b * 2048 + (i0 + il) * 32 + c], v);
  }
}

// ----------------------------------------------------------- mode mix ----
// grid (B), block 256. Reads fp32 xf[b][i][32] from XFY, writes packed
// yk [b][o][32] (k<16: fac*yr, k>=16: fac*yi) back into the SAME region.
__global__ __launch_bounds__(256) void k_mix(
    const float* __restrict__ wr_, const float* __restrict__ wi_,
    float* __restrict__ xfy) {
  int tid = threadIdx.x;
  int b = blockIdx.x;
  __shared__ float xr[HID * MODES], xi[HID * MODES];
  const float* xfb = xfy + (size_t)b * 2048;
  for (int u = tid; u < HID * MODES; u += 256) {
    int i = u >> 4, m = u & 15;
    xr[u] = xfb[i * 32 + m];
    xi[u] = xfb[i * 32 + 16 + m];
  }
  __syncthreads();
  const float invS = 1.0f / (float)S_;
  unsigned* yk = (unsigned*)xfy + (size_t)b * 2048;
  #pragma unroll
  for (int pp = 0; pp < 4; ++pp) {
    int p = pp * 256 + tid;
    int o = p >> 4, m = p & 15;
    float yr = 0.f, yi = 0.f;
    for (int i2 = 0; i2 < HID; ++i2) {
      float wr = wr_[(i2 * HID + o) * MODES + m];
      float wi = wi_[(i2 * HID + o) * MODES + m];
      float xrv = xr[i2 * MODES + m], xiv = xi[i2 * MODES + m];
      yr += xrv * wr - xiv * wi;
      yi += xrv * wi + xiv * wr;
    }
    float fac = (m == 0) ? invS : 2.f * invS;
    yk[o * 32 + m]      = packsplit(yr * fac);
    yk[o * 32 + 16 + m] = packsplit(yi * fac);
  }
}

// --------------------------------------------- irfft + skip + (gelu) ----
// grid (S/256, B), block 256 (4 waves). Wave owns 64 s-cols (nt=4), M=64.
// irfft: A = packed yk[b][o][32], B = Etab[s][32] (one K=32 step).
// skip:  A = split skip_w [o][c],  B = packed h[c][s] direct from global.
// In-place safe: wave-private columns.  (r8-proven)
template <bool ACT>
__global__ __launch_bounds__(256, 2) void k_spec_skip(
    const unsigned short* __restrict__ Shi,
    const unsigned short* __restrict__ Slo,
    const float* __restrict__ skb,
    const unsigned* __restrict__ Yk,
    const unsigned* __restrict__ Etab,
    unsigned* __restrict__ Hp) {
  int tid = threadIdx.x;
  int s0 = blockIdx.x * 256, b = blockIdx.y;
  int lane = tid & 63, wv = tid >> 6, quad = lane >> 4, n16 = lane & 15;
  int sw = s0 + wv * 64;
  // A-frags: skip weights (held in regs for all mt,kk) + yk
  short8 skh[4][2], skl[4][2], yh[4], yl[4];
  #pragma unroll
  for (int mt = 0; mt < 4; ++mt) {
    #pragma unroll
    for (int kk = 0; kk < 2; ++kk) {
      int off = (mt * 16 + n16) * 64 + kk * 32 + quad * 8;
      skh[mt][kk] = *(const short8*)(Shi + off);
      skl[mt][kk] = *(const short8*)(Slo + off);
    }
    uint8v yv = *(const uint8v*)(Yk + (size_t)b * 2048 + (mt * 16 + n16) * 32 + quad * 8);
    #pragma unroll
    for (int j = 0; j < 8; ++j) {
      unsigned u = yv[j];
      yh[mt][j] = (short)(u & 0xffffu); yl[mt][j] = (short)(u >> 16);
    }
  }
  f32x4 acc[4][4];
  #pragma unroll
  for (int mt = 0; mt < 4; ++mt)
    #pragma unroll
    for (int nt = 0; nt < 4; ++nt) acc[mt][nt] = (f32x4){0.f,0.f,0.f,0.f};
  // irfft: one K=32 step per nt
  #pragma unroll
  for (int nt = 0; nt < 4; ++nt) {
    int sc = sw + nt * 16 + n16;
    uint8v tv = *(const uint8v*)(Etab + (size_t)sc * 32 + quad * 8);
    short8 th, tl;
    #pragma unroll
    for (int j = 0; j < 8; ++j) {
      unsigned u = tv[j];
      th[j] = (short)(u & 0xffffu); tl[j] = (short)(u >> 16);
    }
    #pragma unroll
    for (int mt = 0; mt < 4; ++mt) {
      acc[mt][nt] = MFMA16(yh[mt], th, acc[mt][nt], 0, 0, 0);
      acc[mt][nt] = MFMA16(yh[mt], tl, acc[mt][nt], 0, 0, 0);
      acc[mt][nt] = MFMA16(yl[mt], th, acc[mt][nt], 0, 0, 0);
    }
  }
  // skip GEMM: K=64 (2 ksteps), B = packed h from global
  const unsigned* hb = Hp + (size_t)b * HID * S_;
  #pragma unroll
  for (int kk = 0; kk < 2; ++kk) {
    #pragma unroll
    for (int nt = 0; nt < 4; ++nt) {
      int sc = sw + nt * 16 + n16;
      unsigned pk[8];
      #pragma unroll
      for (int j = 0; j < 8; ++j)
        pk[j] = hb[(size_t)(kk * 32 + quad * 8 + j) * S_ + sc];
      short8 bh, bl;
      unpk8(pk, bh, bl);
      #pragma unroll
      for (int mt = 0; mt < 4; ++mt) {
        acc[mt][nt] = MFMA16(skh[mt][kk], bh, acc[mt][nt], 0, 0, 0);
        acc[mt][nt] = MFMA16(skh[mt][kk], bl, acc[mt][nt], 0, 0, 0);
        acc[mt][nt] = MFMA16(skl[mt][kk], bh, acc[mt][nt], 0, 0, 0);
      }
    }
  }
  // epilogue: bias + (gelu) + pack + store
  #pragma unroll
  for (int mt = 0; mt < 4; ++mt) {
    int o0 = mt * 16 + quad * 4;
    float4 bb = *(const float4*)&skb[o0];
    #pragma unroll
    for (int nt = 0; nt < 4; ++nt) {
      int sc = sw + nt * 16 + n16;
      #pragma unroll
      for (int r = 0; r < 4; ++r) {
        float v = acc[mt][nt][r] + ((const float*)&bb)[r];
        if (ACT) v = gelu_f(v);
        Hp[(size_t)(b * HID + o0 + r) * S_ + sc] = packsplit(v);
      }
    }
  }
}

// ------------------------------------------------- projection + mean ----
// grid (S/64, B, 2), block 256 (4 waves), (256,2) — the ONLY safe bound.
// z splits c2: block covers 128 c2-rows (wave owns 32: mt=0..1). Halves
// per-wave MFMA/gelu work; z-halves combine via atomicAdd (2 commutative
// contributors -> deterministic). part zeroed by k_init each call.
__global__ __launch_bounds__(256, 2) void k_proj(
    const unsigned short* __restrict__ Phi,
    const unsigned short* __restrict__ Plo,
    const float* __restrict__ pb1, const float* __restrict__ pw2,
    const unsigned* __restrict__ Hp, float* __restrict__ part) {
  __shared__ unsigned Bp[64 * 65];
  __shared__ float red[12];
  int tid = threadIdx.x;
  int s0 = blockIdx.x * 64, b = blockIdx.y;
  int lane = tid & 63, wv = tid >> 6, quad = lane >> 4, n16 = lane & 15;
  #pragma unroll
  for (int u = 0; u < 16; ++u) {
    int idx = u * 256 + tid;
    int c = idx >> 6, s = idx & 63;
    Bp[c * 65 + s] = Hp[((size_t)b * HID + c) * S_ + s0 + s];
  }
  __syncthreads();
  int m0 = blockIdx.z * 128 + wv * 32;
  f32x4 acc[2][4];
  #pragma unroll
  for (int mt = 0; mt < 2; ++mt)
    #pragma unroll
    for (int nt = 0; nt < 4; ++nt) acc[mt][nt] = (f32x4){0.f,0.f,0.f,0.f};
  #pragma unroll
  for (int kk = 0; kk < 2; ++kk) {
    int kbase = kk * 32 + quad * 8;
    short8 ah[2], al[2];
    #pragma unroll
    for (int mt = 0; mt < 2; ++mt) {
      int aoff = (m0 + mt * 16 + n16) * 64 + kbase;
      ah[mt] = *(const short8*)(Phi + aoff);
      al[mt] = *(const short8*)(Plo + aoff);
    }
    #pragma unroll
    for (int nt = 0; nt < 4; ++nt) {
      int sc = nt * 16 + n16;
      unsigned pk[8];
      #pragma unroll
      for (int j = 0; j < 8; ++j) pk[j] = Bp[(kbase + j) * 65 + sc];
      short8 bh, bl;
      unpk8(pk, bh, bl);
      #pragma unroll
      for (int mt = 0; mt < 2; ++mt) {
        acc[mt][nt] = MFMA16(ah[mt], bh, acc[mt][nt], 0, 0, 0);
        acc[mt][nt] = MFMA16(ah[mt], bl, acc[mt][nt], 0, 0, 0);
        acc[mt][nt] = MFMA16(al[mt], bh, acc[mt][nt], 0, 0, 0);
      }
    }
  }
  float o0 = 0.f, o1 = 0.f, o2 = 0.f;
  #pragma unroll
  for (int mt = 0; mt < 2; ++mt) {
    int c2b = m0 + mt * 16 + quad * 4;
    float4 bb = *(const float4*)&pb1[c2b];
    float4 p0 = *(const float4*)&pw2[c2b];
    float4 p1 = *(const float4*)&pw2[256 + c2b];
    float4 p2 = *(const float4*)&pw2[512 + c2b];
    #pragma unroll
    for (int nt = 0; nt < 4; ++nt) {
      f32x4 a = acc[mt][nt];
      float t0 = gelu_f(a[0] + bb.x);
      float t1 = gelu_f(a[1] + bb.y);
      float t2 = gelu_f(a[2] + bb.z);
      float t3 = gelu_f(a[3] + bb.w);
      o0 += p0.x * t0 + p0.y * t1 + p0.z * t2 + p0.w * t3;
      o1 += p1.x * t0 + p1.y * t1 + p1.z * t2 + p1.w * t3;
      o2 += p2.x * t0 + p2.y * t1 + p2.z * t2 + p2.w * t3;
    }
  }
  #pragma unroll
  for (int off = 32; off > 0; off >>= 1) {
    o0 += __shfl_xor(o0, off, 64);
    o1 += __shfl_xor(o1, off, 64);
    o2 += __shfl_xor(o2, off, 64);
  }
  if (lane == 0) { red[wv*3+0] = o0; red[wv*3+1] = o1; red[wv*3+2] = o2; }
  __syncthreads();
  if (tid < 3) {
    float sum = red[tid] + red[3 + tid] + red[6 + tid] + red[9 + tid];
    atomicAdd(&part[(b * 64 + blockIdx.x) * 3 + tid], sum);
  }
}

__global__ void k_final(const float* __restrict__ part,
                        const float* __restrict__ pb2,
                        float* __restrict__ out) {
  int t = threadIdx.x;
  if (t < B_ * 3) {
    int b = t / 3, j = t % 3;
    float s = 0.f;
    for (int k = 0; k < 64; ++k) s += part[(b * 64 + k) * 3 + j];
    out[t] = s * (1.0f / (float)S_) + pb2[j];
  }
}

// ------------------------------------------------------------- launch ----
extern "C" void kernel_launch(void* const* d_in, const int* in_sizes, int n_in,
                              void* d_out, int out_size, void* d_ws, size_t ws_size,
                              hipStream_t stream) {
  const float* x   = (const float*)d_in[0];
  const float* lw1 = (const float*)d_in[1];
  const float* lb1 = (const float*)d_in[2];
  const float* lw2 = (const float*)d_in[3];
  const float* lb2 = (const float*)d_in[4];
  const float* swr = (const float*)d_in[5];
  const float* swi = (const float*)d_in[6];
  const float* skw = (const float*)d_in[7];
  const float* skb = (const float*)d_in[8];
  const float* pw1 = (const float*)d_in[9];
  const float* pb1 = (const float*)d_in[10];
  const float* pw2 = (const float*)d_in[11];
  const float* pb2 = (const float*)d_in[12];
  float* ws = (float*)d_ws;
  unsigned* Hp  = (unsigned*)(ws + OFF_H);
  unsigned* ETB = (unsigned*)(ws + OFF_ETB);
  float*    XFY = ws + OFF_XFY;

  k_init<<<256, 256, 0, stream>>>(lw2, skw, pw1, lw1, lb1, ws);
  k_lift<<<dim3(S_ / 256, B_), 256, 0, stream>>>(
      x, (const float4*)(ws + OFF_W1B), lb2,
      (const unsigned short*)(ws + OFF_W2HI),
      (const unsigned short*)(ws + OFF_W2LO), Hp);
  for (int l = 0; l < NL; ++l) {
    hipMemsetAsync(XFY, 0, (size_t)B_ * 2048 * sizeof(float), stream);
    k_fft_fwd<<<dim3(4, B_, 4), 256, 0, stream>>>(Hp, ETB, XFY);
    k_mix<<<B_, 256, 0, stream>>>(swr + l * HID * HID * MODES,
                                  swi + l * HID * HID * MODES, XFY);
    if (l < NL - 1)
      k_spec_skip<true><<<dim3(S_ / 256, B_), 256, 0, stream>>>(
          (const unsigned short*)(ws + OFF_SKH) + l * HID * HID,
          (const unsigned short*)(ws + OFF_SKL) + l * HID * HID,
          skb + l * HID, (const unsigned*)XFY, ETB, Hp);
    else
      k_spec_skip<false><<<dim3(S_ / 256, B_), 256, 0, stream>>>(
          (const unsigned short*)(ws + OFF_SKH) + l * HID * HID,
          (const unsigned short*)(ws + OFF_SKL) + l * HID * HID,
          skb + l * HID, (const unsigned*)XFY, ETB, Hp);
  }
  k_proj<<<dim3(S_ / 64, B_, 2), 256, 0, stream>>>(
      (const unsigned short*)(ws + OFF_P1HI),
      (const unsigned short*)(ws + OFF_P1LO),
      pb1, pw2, Hp, ws + OFF_PART);
  k_final<<<1, 256, 0, stream>>>(ws + OFF_PART, pb2, (float*)d_out);
}

// Round 14
// 544.168 us; speedup vs baseline: 1.0451x; 1.0451x over previous
//
#include <hip/hip_runtime.h>
#include <math.h>

// Problem constants
#define B_    64
#define S_    4096
#define HID   64
#define LIFT  256
#define MODES 16
#define NL    4

// Workspace layout (float-sized slots). Total 17,101,824 <= proven 17,108,992.
#define OFF_H     0                       // packed h (uint): B*HID*S = 16,777,216
#define OFF_ETB   16777216                // packed twiddles Etab[s][32]: 131,072
#define OFF_XFY   (OFF_ETB + 131072)      // xf fp32 [b][i][32] OR packed yk [b][o][32]
#define OFF_SKH   (OFF_XFY + 131072)      // ushort skip hi [l][o][c]: 8192 floats
#define OFF_SKL   (OFF_SKH + 8192)
#define OFF_W2HI  (OFF_SKL + 8192)        // ushort lift w2 hi [o][c2]
#define OFF_W2LO  (OFF_W2HI + 8192)
#define OFF_P1HI  (OFF_W2LO + 8192)       // ushort proj w1 hi [c2][c]
#define OFF_P1LO  (OFF_P1HI + 8192)
#define OFF_PART  (OFF_P1LO + 8192)       // 12,288 (atomic-accumulated)
#define OFF_W1B   (OFF_PART + 12288)      // float4[256]: (w1x, w1y, b1, 0)

typedef short short8 __attribute__((ext_vector_type(8)));
typedef float f32x4  __attribute__((ext_vector_type(4)));
typedef unsigned uint8v __attribute__((ext_vector_type(8)));
#define MFMA16 __builtin_amdgcn_mfma_f32_16x16x32_bf16

// libm erff: measured faster than A&S-7.1.26 w/ __frcp_rn on gfx950 (r13).
__device__ __forceinline__ float gelu_f(float x) {
  return 0.5f * x * (1.0f + erff(x * 0.70710678118654752440f));
}
__device__ __forceinline__ unsigned short f2bf(float x) {   // RNE
  unsigned u = __float_as_uint(x);
  u += 0x7fffu + ((u >> 16) & 1u);
  return (unsigned short)(u >> 16);
}
__device__ __forceinline__ float bf2f(unsigned short b) {
  return __uint_as_float(((unsigned)b) << 16);
}
__device__ __forceinline__ unsigned packsplit(float x) {    // hi | lo<<16
  unsigned short hi = f2bf(x);
  unsigned short lo = f2bf(x - bf2f(hi));
  return (unsigned)hi | ((unsigned)lo << 16);
}
__device__ __forceinline__ void unpk8(const unsigned* pk, short8& h8, short8& l8) {
  #pragma unroll
  for (int j = 0; j < 8; ++j) {
    unsigned u = pk[j];
    h8[j] = (short)(u & 0xffffu);
    l8[j] = (short)(u >> 16);
  }
}

// ---------------------------------------------------------------- init ----
// grid 256. Twiddles via sincosf (bf16-split pack error dominates).
__global__ void k_init(const float* __restrict__ lift_w2,
                       const float* __restrict__ skip_w,
                       const float* __restrict__ proj_w1,
                       const float* __restrict__ lift_w1,
                       const float* __restrict__ lift_b1,
                       float* __restrict__ ws) {
  unsigned* etab = (unsigned*)(ws + OFF_ETB);
  unsigned short* skh = (unsigned short*)(ws + OFF_SKH);
  unsigned short* skl = (unsigned short*)(ws + OFF_SKL);
  unsigned short* w2hi = (unsigned short*)(ws + OFF_W2HI);
  unsigned short* w2lo = (unsigned short*)(ws + OFF_W2LO);
  unsigned short* p1hi = (unsigned short*)(ws + OFF_P1HI);
  unsigned short* p1lo = (unsigned short*)(ws + OFF_P1LO);
  float4* w1b = (float4*)(ws + OFF_W1B);
  int idx = blockIdx.x * 256 + threadIdx.x;
  int stride = gridDim.x * 256;
  // Etab[s][c]: c<16 -> cos(th*m*s), c>=16 -> -sin(th*m*s), m = c&15 (s-major)
  for (int k = idx; k < 4096 * 32; k += stride) {
    int s = k >> 5, c = k & 31;
    int m = c & 15;
    int r = (m * s) & 4095;
    float th = (float)(2.0 * 3.14159265358979323846 / 4096.0) * (float)r;
    float sn, cn; sincosf(th, &sn, &cn);
    float v = (c < 16) ? cn : -sn;
    etab[k] = packsplit(v);
  }
  for (int k = idx; k < NL * HID * HID; k += stride) {  // natural [l][o][c]
    float w = skip_w[k];
    unsigned short hi = f2bf(w);
    skh[k] = hi; skl[k] = f2bf(w - bf2f(hi));
  }
  for (int k = idx; k < HID * LIFT; k += stride) {      // natural [o][c2]
    float w = lift_w2[k];
    unsigned short hi = f2bf(w);
    w2hi[k] = hi; w2lo[k] = f2bf(w - bf2f(hi));
  }
  for (int k = idx; k < LIFT * HID; k += stride) {      // natural [c2][c]
    float w = proj_w1[k];
    unsigned short hi = f2bf(w);
    p1hi[k] = hi; p1lo[k] = f2bf(w - bf2f(hi));
  }
  for (int k = idx; k < LIFT; k += stride) {            // packed lift stage-1
    w1b[k] = make_float4(lift_w1[2 * k], lift_w1[2 * k + 1], lift_b1[k], 0.f);
  }
  for (int k = idx; k < 12288; k += stride)             // zero part (atomics)
    ws[OFF_PART + k] = 0.f;
}

// ---------------------------------------------------------------- lift ----
// grid (S/256, B), block 256 (4 waves). Wave owns 64 s-cols (nt=0..3);
// per kstep the 8 A-frags + 8 W1B rows are loaded ONCE and amortized over
// 4 gelu-bursts + 48 MFMAs.  (r8-proven)
__global__ __launch_bounds__(256, 2) void k_lift(
    const float* __restrict__ x, const float4* __restrict__ W1B,
    const float* __restrict__ b2,
    const unsigned short* __restrict__ Whi,
    const unsigned short* __restrict__ Wlo,
    unsigned* __restrict__ Hp) {
  int tid = threadIdx.x;
  int b = blockIdx.y, s0 = blockIdx.x * 256;
  int lane = tid & 63, wv = tid >> 6, quad = lane >> 4, n16 = lane & 15;
  int sw = s0 + wv * 64;
  int cq = quad * 8;    // lane's j-base inside each 32-row K-chunk
  float2 xv[4];
  #pragma unroll
  for (int nt = 0; nt < 4; ++nt)
    xv[nt] = ((const float2*)x)[b * S_ + sw + nt * 16 + n16];
  f32x4 acc[4][4];
  #pragma unroll
  for (int mt = 0; mt < 4; ++mt)
    #pragma unroll
    for (int nt = 0; nt < 4; ++nt) acc[mt][nt] = (f32x4){0.f, 0.f, 0.f, 0.f};

  #pragma unroll 1
  for (int k = 0; k < 8; ++k) {
    short8 ah[4], al[4];
    #pragma unroll
    for (int mt = 0; mt < 4; ++mt) {
      int aoff = (mt * 16 + n16) * 256 + k * 32 + cq;
      ah[mt] = *(const short8*)(Whi + aoff);
      al[mt] = *(const short8*)(Wlo + aoff);
    }
    float4 w[8];
    #pragma unroll
    for (int j = 0; j < 8; ++j) w[j] = W1B[k * 32 + cq + j];
    #pragma unroll
    for (int nt = 0; nt < 4; ++nt) {
      short8 bh, bl;
      #pragma unroll
      for (int j = 0; j < 8; ++j) {
        float t = gelu_f(w[j].x * xv[nt].x + w[j].y * xv[nt].y + w[j].z);
        unsigned pk = packsplit(t);
        bh[j] = (short)(pk & 0xffffu);
        bl[j] = (short)(pk >> 16);
      }
      #pragma unroll
      for (int mt = 0; mt < 4; ++mt) {
        acc[mt][nt] = MFMA16(ah[mt], bh, acc[mt][nt], 0, 0, 0);
        acc[mt][nt] = MFMA16(ah[mt], bl, acc[mt][nt], 0, 0, 0);
        acc[mt][nt] = MFMA16(al[mt], bh, acc[mt][nt], 0, 0, 0);
      }
    }
  }
  #pragma unroll
  for (int mt = 0; mt < 4; ++mt) {
    int o0 = mt * 16 + quad * 4;
    float4 bb = *(const float4*)&b2[o0];
    #pragma unroll
    for (int nt = 0; nt < 4; ++nt) {
      int sc = sw + nt * 16 + n16;
      unsigned* hp = Hp + ((size_t)b * HID + o0) * S_ + sc;
      hp[0]            = packsplit(acc[mt][nt][0] + bb.x);
      hp[(size_t)S_]   = packsplit(acc[mt][nt][1] + bb.y);
      hp[(size_t)2*S_] = packsplit(acc[mt][nt][2] + bb.z);
      hp[(size_t)3*S_] = packsplit(acc[mt][nt][3] + bb.w);
    }
  }
}

// --------------------------------------------------------- forward DFT ----
// grid (4 msplit, B, 4 ksplit), block 256 (4 waves) -> 1024 blocks, 4/CU.
// Wave g = ks*4+wv covers K-range [g*256, +256). Block partial is LDS-
// reduced then atomicAdd'ed into xf (16 commutative fp32 contributors).
// xf zeroed per layer by hipMemsetAsync before this kernel.
__global__ __launch_bounds__(256, 4) void k_fft_fwd(
    const unsigned* __restrict__ Hp, const unsigned* __restrict__ Etab,
    float* __restrict__ xf) {
  __shared__ float red[4 * 512];
  int tid = threadIdx.x;
  int i0 = blockIdx.x * 16, b = blockIdx.y, ks = blockIdx.z;
  int lane = tid & 63, wv = tid >> 6, quad = lane >> 4, n16 = lane & 15;
  const unsigned* hb = Hp + ((size_t)b * HID + i0 + n16) * S_;
  int g = ks * 4 + wv;               // K-chunk 0..15
  f32x4 acc0 = (f32x4){0.f,0.f,0.f,0.f}, acc1 = (f32x4){0.f,0.f,0.f,0.f};
  #pragma unroll 1
  for (int kt = 0; kt < 8; ++kt) {
    int sb = g * 256 + kt * 32 + quad * 8;
    uint8v av = *(const uint8v*)(hb + sb);
    short8 ah, al;
    #pragma unroll
    for (int j = 0; j < 8; ++j) {
      unsigned u = av[j];
      ah[j] = (short)(u & 0xffffu); al[j] = (short)(u >> 16);
    }
    unsigned q0[8], q1[8];
    #pragma unroll
    for (int j = 0; j < 8; ++j) {
      q0[j] = Etab[(sb + j) * 32 + n16];
      q1[j] = Etab[(sb + j) * 32 + 16 + n16];
    }
    short8 bh0, bl0, bh1, bl1;
    unpk8(q0, bh0, bl0);
    unpk8(q1, bh1, bl1);
    acc0 = MFMA16(ah, bh0, acc0, 0, 0, 0);
    acc0 = MFMA16(ah, bl0, acc0, 0, 0, 0);
    acc0 = MFMA16(al, bh0, acc0, 0, 0, 0);
    acc1 = MFMA16(ah, bh1, acc1, 0, 0, 0);
    acc1 = MFMA16(ah, bl1, acc1, 0, 0, 0);
    acc1 = MFMA16(al, bh1, acc1, 0, 0, 0);
  }
  // D: row = quad*4+r (i_local), col = n16 (+16 for acc1)
  #pragma unroll
  for (int r = 0; r < 4; ++r) {
    red[wv * 512 + (quad * 4 + r) * 32 + n16]      = acc0[r];
    red[wv * 512 + (quad * 4 + r) * 32 + 16 + n16] = acc1[r];
  }
  __syncthreads();
  #pragma unroll
  for (int u = 0; u < 2; ++u) {
    int t = u * 256 + tid;
    int il = t >> 5, c = t & 31;
    float v = red[t] + red[512 + t] + red[1024 + t] + red[1536 + t];
    atomicAdd(&xf[(size_t)b * 2048 + (i0 + il) * 32 + c], v);
  }
}

// ----------------------------------------------------------- mode mix ----
// grid (B), block 256. Reads fp32 xf[b][i][32] from XFY, writes packed
// yk [b][o][32] (k<16: fac*yr, k>=16: fac*yi) back into the SAME region.
__global__ __launch_bounds__(256) void k_mix(
    const float* __restrict__ wr_, const float* __restrict__ wi_,
    float* __restrict__ xfy) {
  int tid = threadIdx.x;
  int b = blockIdx.x;
  __shared__ float xr[HID * MODES], xi[HID * MODES];
  const float* xfb = xfy + (size_t)b * 2048;
  for (int u = tid; u < HID * MODES; u += 256) {
    int i = u >> 4, m = u & 15;
    xr[u] = xfb[i * 32 + m];
    xi[u] = xfb[i * 32 + 16 + m];
  }
  __syncthreads();
  const float invS = 1.0f / (float)S_;
  unsigned* yk = (unsigned*)xfy + (size_t)b * 2048;
  #pragma unroll
  for (int pp = 0; pp < 4; ++pp) {
    int p = pp * 256 + tid;
    int o = p >> 4, m = p & 15;
    float yr = 0.f, yi = 0.f;
    for (int i2 = 0; i2 < HID; ++i2) {
      float wr = wr_[(i2 * HID + o) * MODES + m];
      float wi = wi_[(i2 * HID + o) * MODES + m];
      float xrv = xr[i2 * MODES + m], xiv = xi[i2 * MODES + m];
      yr += xrv * wr - xiv * wi;
      yi += xrv * wi + xiv * wr;
    }
    float fac = (m == 0) ? invS : 2.f * invS;
    yk[o * 32 + m]      = packsplit(yr * fac);
    yk[o * 32 + 16 + m] = packsplit(yi * fac);
  }
}

// --------------------------------------------- irfft + skip + (gelu) ----
// grid (S/256, B), block 256 (4 waves). Wave owns 64 s-cols (nt=4), M=64.
// Register-lean phasing: irfft first (yk frags scoped, die after), skip
// A-frags loaded per-kk (8 live short8 instead of 16+8). (256,2) keeps the
// no-spill guarantee; if the compiler lands <=170 VGPR, occupancy rises to
// 3 waves/SIMD organically. In-place safe: wave-private columns.
template <bool ACT>
__global__ __launch_bounds__(256, 2) void k_spec_skip(
    const unsigned short* __restrict__ Shi,
    const unsigned short* __restrict__ Slo,
    const float* __restrict__ skb,
    const unsigned* __restrict__ Yk,
    const unsigned* __restrict__ Etab,
    unsigned* __restrict__ Hp) {
  int tid = threadIdx.x;
  int s0 = blockIdx.x * 256, b = blockIdx.y;
  int lane = tid & 63, wv = tid >> 6, quad = lane >> 4, n16 = lane & 15;
  int sw = s0 + wv * 64;
  f32x4 acc[4][4];
  #pragma unroll
  for (int mt = 0; mt < 4; ++mt)
    #pragma unroll
    for (int nt = 0; nt < 4; ++nt) acc[mt][nt] = (f32x4){0.f,0.f,0.f,0.f};
  // ---- irfft phase: yk A-frags live only in this scope ----
  {
    short8 yh[4], yl[4];
    #pragma unroll
    for (int mt = 0; mt < 4; ++mt) {
      uint8v yv = *(const uint8v*)(Yk + (size_t)b * 2048 + (mt * 16 + n16) * 32 + quad * 8);
      #pragma unroll
      for (int j = 0; j < 8; ++j) {
        unsigned u = yv[j];
        yh[mt][j] = (short)(u & 0xffffu); yl[mt][j] = (short)(u >> 16);
      }
    }
    #pragma unroll
    for (int nt = 0; nt < 4; ++nt) {
      int sc = sw + nt * 16 + n16;
      uint8v tv = *(const uint8v*)(Etab + (size_t)sc * 32 + quad * 8);
      short8 th, tl;
      #pragma unroll
      for (int j = 0; j < 8; ++j) {
        unsigned u = tv[j];
        th[j] = (short)(u & 0xffffu); tl[j] = (short)(u >> 16);
      }
      #pragma unroll
      for (int mt = 0; mt < 4; ++mt) {
        acc[mt][nt] = MFMA16(yh[mt], th, acc[mt][nt], 0, 0, 0);
        acc[mt][nt] = MFMA16(yh[mt], tl, acc[mt][nt], 0, 0, 0);
        acc[mt][nt] = MFMA16(yl[mt], th, acc[mt][nt], 0, 0, 0);
      }
    }
  }
  // ---- skip GEMM: K=64 (2 ksteps); A-frags loaded per-kk ----
  const unsigned* hb = Hp + (size_t)b * HID * S_;
  #pragma unroll
  for (int kk = 0; kk < 2; ++kk) {
    short8 skh[4], skl[4];
    #pragma unroll
    for (int mt = 0; mt < 4; ++mt) {
      int off = (mt * 16 + n16) * 64 + kk * 32 + quad * 8;
      skh[mt] = *(const short8*)(Shi + off);
      skl[mt] = *(const short8*)(Slo + off);
    }
    #pragma unroll
    for (int nt = 0; nt < 4; ++nt) {
      int sc = sw + nt * 16 + n16;
      unsigned pk[8];
      #pragma unroll
      for (int j = 0; j < 8; ++j)
        pk[j] = hb[(size_t)(kk * 32 + quad * 8 + j) * S_ + sc];
      short8 bh, bl;
      unpk8(pk, bh, bl);
      #pragma unroll
      for (int mt = 0; mt < 4; ++mt) {
        acc[mt][nt] = MFMA16(skh[mt], bh, acc[mt][nt], 0, 0, 0);
        acc[mt][nt] = MFMA16(skh[mt], bl, acc[mt][nt], 0, 0, 0);
        acc[mt][nt] = MFMA16(skl[mt], bh, acc[mt][nt], 0, 0, 0);
      }
    }
  }
  // epilogue: bias + (gelu) + pack + store
  #pragma unroll
  for (int mt = 0; mt < 4; ++mt) {
    int o0 = mt * 16 + quad * 4;
    float4 bb = *(const float4*)&skb[o0];
    #pragma unroll
    for (int nt = 0; nt < 4; ++nt) {
      int sc = sw + nt * 16 + n16;
      #pragma unroll
      for (int r = 0; r < 4; ++r) {
        float v = acc[mt][nt][r] + ((const float*)&bb)[r];
        if (ACT) v = gelu_f(v);
        Hp[(size_t)(b * HID + o0 + r) * S_ + sc] = packsplit(v);
      }
    }
  }
}

// ------------------------------------------------- projection + mean ----
// grid (S/64, B, 2), block 256 (4 waves), (256,2) — the ONLY safe bound.
// z splits c2: block covers 128 c2-rows (wave owns 32: mt=0..1). Halves
// per-wave MFMA/gelu work; z-halves combine via atomicAdd (2 commutative
// contributors -> deterministic). part zeroed by k_init each call.
__global__ __launch_bounds__(256, 2) void k_proj(
    const unsigned short* __restrict__ Phi,
    const unsigned short* __restrict__ Plo,
    const float* __restrict__ pb1, const float* __restrict__ pw2,
    const unsigned* __restrict__ Hp, float* __restrict__ part) {
  __shared__ unsigned Bp[64 * 65];
  __shared__ float red[12];
  int tid = threadIdx.x;
  int s0 = blockIdx.x * 64, b = blockIdx.y;
  int lane = tid & 63, wv = tid >> 6, quad = lane >> 4, n16 = lane & 15;
  #pragma unroll
  for (int u = 0; u < 16; ++u) {
    int idx = u * 256 + tid;
    int c = idx >> 6, s = idx & 63;
    Bp[c * 65 + s] = Hp[((size_t)b * HID + c) * S_ + s0 + s];
  }
  __syncthreads();
  int m0 = blockIdx.z * 128 + wv * 32;
  f32x4 acc[2][4];
  #pragma unroll
  for (int mt = 0; mt < 2; ++mt)
    #pragma unroll
    for (int nt = 0; nt < 4; ++nt) acc[mt][nt] = (f32x4){0.f,0.f,0.f,0.f};
  #pragma unroll
  for (int kk = 0; kk < 2; ++kk) {
    int kbase = kk * 32 + quad * 8;
    short8 ah[2], al[2];
    #pragma unroll
    for (int mt = 0; mt < 2; ++mt) {
      int aoff = (m0 + mt * 16 + n16) * 64 + kbase;
      ah[mt] = *(const short8*)(Phi + aoff);
      al[mt] = *(const short8*)(Plo + aoff);
    }
    #pragma unroll
    for (int nt = 0; nt < 4; ++nt) {
      int sc = nt * 16 + n16;
      unsigned pk[8];
      #pragma unroll
      for (int j = 0; j < 8; ++j) pk[j] = Bp[(kbase + j) * 65 + sc];
      short8 bh, bl;
      unpk8(pk, bh, bl);
      #pragma unroll
      for (int mt = 0; mt < 2; ++mt) {
        acc[mt][nt] = MFMA16(ah[mt], bh, acc[mt][nt], 0, 0, 0);
        acc[mt][nt] = MFMA16(ah[mt], bl, acc[mt][nt], 0, 0, 0);
        acc[mt][nt] = MFMA16(al[mt], bh, acc[mt][nt], 0, 0, 0);
      }
    }
  }
  float o0 = 0.f, o1 = 0.f, o2 = 0.f;
  #pragma unroll
  for (int mt = 0; mt < 2; ++mt) {
    int c2b = m0 + mt * 16 + quad * 4;
    float4 bb = *(const float4*)&pb1[c2b];
    float4 p0 = *(const float4*)&pw2[c2b];
    float4 p1 = *(const float4*)&pw2[256 + c2b];
    float4 p2 = *(const float4*)&pw2[512 + c2b];
    #pragma unroll
    for (int nt = 0; nt < 4; ++nt) {
      f32x4 a = acc[mt][nt];
      float t0 = gelu_f(a[0] + bb.x);
      float t1 = gelu_f(a[1] + bb.y);
      float t2 = gelu_f(a[2] + bb.z);
      float t3 = gelu_f(a[3] + bb.w);
      o0 += p0.x * t0 + p0.y * t1 + p0.z * t2 + p0.w * t3;
      o1 += p1.x * t0 + p1.y * t1 + p1.z * t2 + p1.w * t3;
      o2 += p2.x * t0 + p2.y * t1 + p2.z * t2 + p2.w * t3;
    }
  }
  #pragma unroll
  for (int off = 32; off > 0; off >>= 1) {
    o0 += __shfl_xor(o0, off, 64);
    o1 += __shfl_xor(o1, off, 64);
    o2 += __shfl_xor(o2, off, 64);
  }
  if (lane == 0) { red[wv*3+0] = o0; red[wv*3+1] = o1; red[wv*3+2] = o2; }
  __syncthreads();
  if (tid < 3) {
    float sum = red[tid] + red[3 + tid] + red[6 + tid] + red[9 + tid];
    atomicAdd(&part[(b * 64 + blockIdx.x) * 3 + tid], sum);
  }
}

__global__ void k_final(const float* __restrict__ part,
                        const float* __restrict__ pb2,
                        float* __restrict__ out) {
  int t = threadIdx.x;
  if (t < B_ * 3) {
    int b = t / 3, j = t % 3;
    float s = 0.f;
    for (int k = 0; k < 64; ++k) s += part[(b * 64 + k) * 3 + j];
    out[t] = s * (1.0f / (float)S_) + pb2[j];
  }
}

// ------------------------------------------------------------- launch ----
extern "C" void kernel_launch(void* const* d_in, const int* in_sizes, int n_in,
                              void* d_out, int out_size, void* d_ws, size_t ws_size,
                              hipStream_t stream) {
  const float* x   = (const float*)d_in[0];
  const float* lw1 = (const float*)d_in[1];
  const float* lb1 = (const float*)d_in[2];
  const float* lw2 = (const float*)d_in[3];
  const float* lb2 = (const float*)d_in[4];
  const float* swr = (const float*)d_in[5];
  const float* swi = (const float*)d_in[6];
  const float* skw = (const float*)d_in[7];
  const float* skb = (const float*)d_in[8];
  const float* pw1 = (const float*)d_in[9];
  const float* pb1 = (const float*)d_in[10];
  const float* pw2 = (const float*)d_in[11];
  const float* pb2 = (const float*)d_in[12];
  float* ws = (float*)d_ws;
  unsigned* Hp  = (unsigned*)(ws + OFF_H);
  unsigned* ETB = (unsigned*)(ws + OFF_ETB);
  float*    XFY = ws + OFF_XFY;

  k_init<<<256, 256, 0, stream>>>(lw2, skw, pw1, lw1, lb1, ws);
  k_lift<<<dim3(S_ / 256, B_), 256, 0, stream>>>(
      x, (const float4*)(ws + OFF_W1B), lb2,
      (const unsigned short*)(ws + OFF_W2HI),
      (const unsigned short*)(ws + OFF_W2LO), Hp);
  for (int l = 0; l < NL; ++l) {
    hipMemsetAsync(XFY, 0, (size_t)B_ * 2048 * sizeof(float), stream);
    k_fft_fwd<<<dim3(4, B_, 4), 256, 0, stream>>>(Hp, ETB, XFY);
    k_mix<<<B_, 256, 0, stream>>>(swr + l * HID * HID * MODES,
                                  swi + l * HID * HID * MODES, XFY);
    if (l < NL - 1)
      k_spec_skip<true><<<dim3(S_ / 256, B_), 256, 0, stream>>>(
          (const unsigned short*)(ws + OFF_SKH) + l * HID * HID,
          (const unsigned short*)(ws + OFF_SKL) + l * HID * HID,
          skb + l * HID, (const unsigned*)XFY, ETB, Hp);
    else
      k_spec_skip<false><<<dim3(S_ / 256, B_), 256, 0, stream>>>(
          (const unsigned short*)(ws + OFF_SKH) + l * HID * HID,
          (const unsigned short*)(ws + OFF_SKL) + l * HID * HID,
          skb + l * HID, (const unsigned*)XFY, ETB, Hp);
  }
  k_proj<<<dim3(S_ / 64, B_, 2), 256, 0, stream>>>(
      (const unsigned short*)(ws + OFF_P1HI),
      (const unsigned short*)(ws + OFF_P1LO),
      pb1, pw2, Hp, ws + OFF_PART);
  k_final<<<1, 256, 0, stream>>>(ws + OFF_PART, pb2, (float*)d_out);
}